// Round 5
// baseline (1108.239 us; speedup 1.0000x reference)
//
#include <hip/hip_runtime.h>
#include <hip/hip_bf16.h>
#include <float.h>

#define BATCH 8
#define CDIM 64
#define NPTS 4096
#define KNN 20
#define KSEL 32
#define NPART 4
#define BN_EPS 1e-5f
#define NEG_SLOPE 0.2f

typedef __attribute__((ext_vector_type(8))) short short8;
typedef __attribute__((ext_vector_type(4))) float float4v;
typedef unsigned short ushort;
typedef unsigned int uint;

__device__ __forceinline__ ushort f2bf(float f) {
    uint u = __float_as_uint(f);
    u += 0x7FFF + ((u >> 16) & 1);            // round-to-nearest-even
    return (ushort)(u >> 16);
}
__device__ __forceinline__ float bf2f(ushort h) {
    return __uint_as_float(((uint)h) << 16);
}

// cheap cross-lane primitives:
__device__ __forceinline__ float dpp_shr1_f(float x) {   // lane i <- lane i-1 (wave_shr:1)
    int xi = __float_as_int(x);
    return __int_as_float(__builtin_amdgcn_update_dpp(xi, xi, 0x138, 0xF, 0xF, false));
}
__device__ __forceinline__ int dpp_shr1_i(int x) {
    return __builtin_amdgcn_update_dpp(x, x, 0x138, 0xF, 0xF, false);
}
__device__ __forceinline__ float rl_f(float v, int l) {  // readlane (uniform result)
    return __int_as_float(__builtin_amdgcn_readlane(__float_as_int(v), l));
}

// ---------------------------------------------------------------------------
// K1: x [B,C,N] -> xt [B,N,64] fp32, xh/xl [B,N,64] bf16 hi/lo split,
//     sq[b,n] = sum_c x^2 (fp32)
// ---------------------------------------------------------------------------
__global__ void k_prep(const float* __restrict__ x,
                       float* __restrict__ xt,
                       ushort* __restrict__ xh,
                       ushort* __restrict__ xl,
                       float* __restrict__ sq) {
    int gid = blockIdx.x * 256 + threadIdx.x;     // [0, B*N)
    int b = gid >> 12;
    int n = gid & (NPTS - 1);
    const float* xb = x + (size_t)b * CDIM * NPTS + n;
    float acc = 0.f;
    float4* xtv = (float4*)(xt + ((size_t)gid << 6));
    uint2* xhp = (uint2*)(xh + ((size_t)gid << 6));
    uint2* xlp = (uint2*)(xl + ((size_t)gid << 6));
    #pragma unroll
    for (int q = 0; q < 16; ++q) {
        float v[4];
        ushort h[4], l[4];
        #pragma unroll
        for (int j = 0; j < 4; ++j) {
            float t = xb[(q * 4 + j) * NPTS];     // coalesced across n
            v[j] = t;
            acc = fmaf(t, t, acc);
            h[j] = f2bf(t);
            l[j] = f2bf(t - bf2f(h[j]));
        }
        xtv[q] = make_float4(v[0], v[1], v[2], v[3]);
        uint2 ph, pl;
        ph.x = (uint)h[0] | ((uint)h[1] << 16);
        ph.y = (uint)h[2] | ((uint)h[3] << 16);
        pl.x = (uint)l[0] | ((uint)l[1] << 16);
        pl.y = (uint)l[2] | ((uint)l[3] << 16);
        xhp[q] = ph;
        xlp[q] = pl;
    }
    sq[gid] = acc;
}

// ---------------------------------------------------------------------------
// K2: p = W1 @ x, z = (W2-W1) @ x, stored transposed: pt/zt [B,N,64]
// ---------------------------------------------------------------------------
__global__ void k_pz(const float* __restrict__ xt, const float* __restrict__ W,
                     float* __restrict__ pt, float* __restrict__ zt) {
    int b  = blockIdx.x >> 6;
    int n0 = (blockIdx.x & 63) << 6;
    int lane = threadIdx.x & 63;
    int w = threadIdx.x >> 6;
    int n = n0 + lane;
    size_t rowoff = ((size_t)(b * NPTS + n)) << 6;
    const float4* xrow = (const float4*)(xt + rowoff);
    float acc1[16], acc2[16];
    #pragma unroll
    for (int i = 0; i < 16; ++i) { acc1[i] = 0.f; acc2[i] = 0.f; }
    #pragma unroll
    for (int cg = 0; cg < 4; ++cg) {
        float xv[16];
        #pragma unroll
        for (int q = 0; q < 4; ++q) {
            float4 t = xrow[cg * 4 + q];
            xv[q*4] = t.x; xv[q*4+1] = t.y; xv[q*4+2] = t.z; xv[q*4+3] = t.w;
        }
        #pragma unroll
        for (int oi = 0; oi < 16; ++oi) {
            int o = (w << 4) + oi;
            const float* wr = W + o * 128 + cg * 16;
            float a1 = acc1[oi], a2 = acc2[oi];
            #pragma unroll
            for (int j = 0; j < 16; ++j) {
                a1 = fmaf(wr[j],      xv[j], a1);
                a2 = fmaf(wr[64 + j], xv[j], a2);
            }
            acc1[oi] = a1; acc2[oi] = a2;
        }
    }
    float4* pv = (float4*)(pt + rowoff + (w << 4));
    float4* zv = (float4*)(zt + rowoff + (w << 4));
    #pragma unroll
    for (int q = 0; q < 4; ++q) {
        pv[q] = make_float4(acc1[q*4], acc1[q*4+1], acc1[q*4+2], acc1[q*4+3]);
        zv[q] = make_float4(acc2[q*4]   - acc1[q*4],
                            acc2[q*4+1] - acc1[q*4+1],
                            acc2[q*4+2] - acc1[q*4+2],
                            acc2[q*4+3] - acc1[q*4+3]);
    }
}

// ---------------------------------------------------------------------------
// K3: approximate kNN, candidate-partitioned top-32 supersets.
// wave = (16 rows) x (1024-candidate partition); 8192 waves total.
// Zero barriers: B-fragments gathered from global (L2-resident), dw tile is
// wave-private LDS. Scalar-tau ballot-insertion keeps sorted top-32 in lanes.
// ---------------------------------------------------------------------------
__global__ void __launch_bounds__(128, 4) k_knn32(
        const ushort* __restrict__ xh, const ushort* __restrict__ xl,
        const float* __restrict__ sq, ushort* __restrict__ knn32) {
    __shared__ float dwall[2][16][68];

    int wslot = threadIdx.x >> 6;
    int wid = blockIdx.x * 2 + wslot;      // [0, 8192)
    int part = wid & (NPART - 1);
    int rg   = (wid >> 2) & 255;
    int b    = wid >> 10;
    int r0   = rg << 4;                    // 16-row group within batch
    int lane = threadIdx.x & 63;
    int col = lane & 15;
    int quad = lane >> 4;
    float (*dw)[68] = dwall[wslot];

    // A fragments: row = r0 + col, k = quad*8 + j
    size_t arow = ((size_t)(b * NPTS + r0 + col)) << 6;
    short8 ah0 = *(const short8*)(xh + arow + quad * 8);
    short8 ah1 = *(const short8*)(xh + arow + 32 + quad * 8);
    short8 al0 = *(const short8*)(xl + arow + quad * 8);
    short8 al1 = *(const short8*)(xl + arow + 32 + quad * 8);

    float dl[16]; int il[16]; float tau[16];
    #pragma unroll
    for (int r = 0; r < 16; ++r) { dl[r] = FLT_MAX; il[r] = 0; tau[r] = FLT_MAX; }

    const ushort* xhb = xh + (((size_t)b * NPTS) << 6);
    const ushort* xlb = xl + (((size_t)b * NPTS) << 6);
    const float* sqb = sq + b * NPTS;
    int vfrag = col * 64 + quad * 8;       // static per-lane fragment offset

    for (int chunk = 0; chunk < 16; ++chunk) {
        int m0 = (part << 10) + (chunk << 6);
        float sv = sqb[m0 + lane];         // candidate sq, lane = candidate

        #pragma unroll
        for (int t = 0; t < 4; ++t) {
            const ushort* ph = xhb + (size_t)(m0 + t * 16) * 64 + vfrag;
            const ushort* pl = xlb + (size_t)(m0 + t * 16) * 64 + vfrag;
            short8 bh0 = *(const short8*)ph;
            short8 bh1 = *(const short8*)(ph + 32);
            short8 bl0 = *(const short8*)pl;
            short8 bl1 = *(const short8*)(pl + 32);
            float4v acc = {0.f, 0.f, 0.f, 0.f};
            acc = __builtin_amdgcn_mfma_f32_16x16x32_bf16(ah0, bh0, acc, 0, 0, 0);
            acc = __builtin_amdgcn_mfma_f32_16x16x32_bf16(ah1, bh1, acc, 0, 0, 0);
            acc = __builtin_amdgcn_mfma_f32_16x16x32_bf16(ah0, bl0, acc, 0, 0, 0);
            acc = __builtin_amdgcn_mfma_f32_16x16x32_bf16(ah1, bl1, acc, 0, 0, 0);
            acc = __builtin_amdgcn_mfma_f32_16x16x32_bf16(al0, bh0, acc, 0, 0, 0);
            acc = __builtin_amdgcn_mfma_f32_16x16x32_bf16(al1, bh1, acc, 0, 0, 0);
            // D layout: col(cand)=lane&15, row=quad*4+r → store -2*inner
            #pragma unroll
            for (int r = 0; r < 4; ++r)
                dw[(quad << 2) + r][(t << 4) + col] = acc[r];
        }

        // transpose via wave-private LDS: lane = candidate
        float dvals[16];
        #pragma unroll
        for (int r = 0; r < 16; ++r)
            dvals[r] = fmaf(-2.f, dw[r][lane], sv);

        #pragma unroll
        for (int r = 0; r < 16; ++r) {
            float d = dvals[r];
            unsigned long long mask = __ballot(d < tau[r]);
            while (mask) {
                int s = __ffsll((long long)mask) - 1;
                mask &= mask - 1;
                float ds = rl_f(d, s);
                if (!(ds < tau[r])) continue;            // scalar check (stale bit)
                unsigned long long gt = __ballot(ds < dl[r]);
                int pos = __ffsll((long long)gt) - 1;    // insertion point <= 31
                float pd = dpp_shr1_f(dl[r]);
                int   pi = dpp_shr1_i(il[r]);
                if (lane >= pos && lane < KSEL) {
                    dl[r] = (lane == pos) ? ds : pd;
                    il[r] = (lane == pos) ? (m0 + s) : pi;
                }
                tau[r] = rl_f(dl[r], KSEL - 1);
            }
        }
    }
    #pragma unroll
    for (int r = 0; r < 16; ++r)
        if (lane < KSEL)
            knn32[((size_t)(b * NPTS + r0 + r) << 7) + (part << 5) + lane] =
                (ushort)il[r];
}

// ---------------------------------------------------------------------------
// K3b: exact refinement over the 128-candidate union — one wave per row,
// 2 candidates/lane; exact fp32 distances; 20 find-min rounds with
// (dist, idx) lexicographic order (np tie rule). Candidates are unique
// (disjoint partitions) so invalidation-by-index is safe.
// ---------------------------------------------------------------------------
__global__ void __launch_bounds__(256) k_refine(
        const float* __restrict__ xt, const float* __restrict__ sq,
        const ushort* __restrict__ knn32, int* __restrict__ idx20) {
    int row = blockIdx.x * 4 + (threadIdx.x >> 6);   // [0, B*N)
    int lane = threadIdx.x & 63;
    int b = row >> 12;
    int c0 = knn32[((size_t)row << 7) + lane];
    int c1 = knn32[((size_t)row << 7) + 64 + lane];
    const float4* xr = (const float4*)(xt + ((size_t)row << 6));
    const float4* x0 = (const float4*)(xt + ((size_t)(b * NPTS + c0) << 6));
    const float4* x1 = (const float4*)(xt + ((size_t)(b * NPTS + c1) << 6));
    float a0 = 0.f, a1 = 0.f;
    #pragma unroll
    for (int q = 0; q < 16; ++q) {
        float4 a = xr[q], u = x0[q], v = x1[q];
        a0 = fmaf(a.x, u.x, a0); a0 = fmaf(a.y, u.y, a0);
        a0 = fmaf(a.z, u.z, a0); a0 = fmaf(a.w, u.w, a0);
        a1 = fmaf(a.x, v.x, a1); a1 = fmaf(a.y, v.y, a1);
        a1 = fmaf(a.z, v.z, a1); a1 = fmaf(a.w, v.w, a1);
    }
    float d0 = fmaf(-2.f, a0, sq[b * NPTS + c0]);
    float d1 = fmaf(-2.f, a1, sq[b * NPTS + c1]);
    #pragma unroll
    for (int i = 0; i < KNN; ++i) {
        bool s0 = (d0 < d1) || (d0 == d1 && c0 < c1);
        float dm = s0 ? d0 : d1;
        int   cm = s0 ? c0 : c1;
        #pragma unroll
        for (int off = 1; off < 64; off <<= 1) {
            float dj = __shfl_xor(dm, off);
            int   cj = __shfl_xor(cm, off);
            bool take = (dj < dm) || (dj == dm && cj < cm);
            dm = take ? dj : dm;
            cm = take ? cj : cm;
        }
        if (lane == 0) idx20[(size_t)row * KNN + i] = cm;
        if (c0 == cm) d0 = FLT_MAX;
        if (c1 == cm) d1 = FLT_MAX;
    }
}

// ---------------------------------------------------------------------------
// K4: gather p columns per neighbor; per-(b,n) max/min/sum/sumsq over k;
// write tmax/tmin = (max/min_k p[idx]) + z; accumulate channel sums.
// ---------------------------------------------------------------------------
__global__ void k_gather(const float* __restrict__ pt, const float* __restrict__ zt,
                         const int* __restrict__ idxin,
                         float* __restrict__ tmax, float* __restrict__ tmin,
                         float* __restrict__ S1, float* __restrict__ S2) {
    __shared__ float red1[4][64];
    __shared__ float red2[4][64];
    int b  = blockIdx.x >> 6;
    int n0 = (blockIdx.x & 63) << 6;
    int lane = threadIdx.x & 63;
    int w = threadIdx.x >> 6;
    float cs1 = 0.f, cs2 = 0.f;
    for (int i = 0; i < 16; ++i) {
        int n = n0 + (w << 4) + i;
        int base = b * NPTS + n;
        int ibase = __builtin_amdgcn_readfirstlane(base * KNN);
        const int* ip = idxin + ibase;
        float mx = -FLT_MAX, mn = FLT_MAX, s1 = 0.f, s2 = 0.f;
        #pragma unroll
        for (int k = 0; k < KNN; ++k) {
            int colp = ip[k];                              // SGPR
            float v = pt[(((size_t)(b * NPTS + colp)) << 6) + lane]; // coalesced
            mx = fmaxf(mx, v); mn = fminf(mn, v);
            s1 += v; s2 = fmaf(v, v, s2);
        }
        float z = zt[(((size_t)base) << 6) + lane];
        tmax[(((size_t)base) << 6) + lane] = mx + z;
        tmin[(((size_t)base) << 6) + lane] = mn + z;
        cs1 += s1 + (float)KNN * z;
        cs2 += s2 + 2.f * z * s1 + (float)KNN * z * z;
    }
    red1[w][lane] = cs1;
    red2[w][lane] = cs2;
    __syncthreads();
    if (threadIdx.x < 64) {
        float t1 = red1[0][lane] + red1[1][lane] + red1[2][lane] + red1[3][lane];
        float t2 = red2[0][lane] + red2[1][lane] + red2[2][lane] + red2[3][lane];
        atomicAdd(&S1[lane], t1);
        atomicAdd(&S2[lane], t2);
    }
}

// ---------------------------------------------------------------------------
// K5: finalize BN stats, affine + LeakyReLU, transpose to out [B,64,N].
// ---------------------------------------------------------------------------
__global__ void k_final(const float* __restrict__ tmax, const float* __restrict__ tmin,
                        const float* __restrict__ S1, const float* __restrict__ S2,
                        const float* __restrict__ gamma, const float* __restrict__ beta,
                        float* __restrict__ out) {
    __shared__ float smx[64][65];
    __shared__ float smn[64][65];
    int b  = blockIdx.x >> 6;
    int n0 = (blockIdx.x & 63) << 6;
    int lane = threadIdx.x & 63;
    int w = threadIdx.x >> 6;
    #pragma unroll
    for (int i = 0; i < 16; ++i) {
        int nl = (i << 2) + w;
        size_t off = (((size_t)(b * NPTS + n0 + nl)) << 6) + lane;
        smx[nl][lane] = tmax[off];
        smn[nl][lane] = tmin[off];
    }
    __syncthreads();
    const float inv_cnt = 1.0f / ((float)BATCH * NPTS * KNN);
    #pragma unroll
    for (int i = 0; i < 16; ++i) {
        int o = (i << 2) + w;
        float s1 = S1[o], s2 = S2[o];
        float mean = s1 * inv_cnt;
        float var = fmaf(-mean, mean, s2 * inv_cnt);
        float rs = rsqrtf(var + BN_EPS);
        float sc = gamma[o] * rs;
        float sh = beta[o] - mean * sc;
        float tv = (sc >= 0.f) ? smx[lane][o] : smn[lane][o];
        float y = fmaf(tv, sc, sh);
        y = (y >= 0.f) ? y : NEG_SLOPE * y;
        out[((size_t)(b * 64 + o)) * NPTS + n0 + lane] = y;
    }
}

// ---------------------------------------------------------------------------
extern "C" void kernel_launch(void* const* d_in, const int* in_sizes, int n_in,
                              void* d_out, int out_size, void* d_ws, size_t ws_size,
                              hipStream_t stream) {
    const float* x     = (const float*)d_in[0];   // [8,64,4096]
    const float* W     = (const float*)d_in[1];   // [64,128]
    const float* gamma = (const float*)d_in[2];   // [64]
    const float* beta  = (const float*)d_in[3];   // [64]
    float* out = (float*)d_out;                   // [8,64,4096]

    float* ws = (float*)d_ws;
    const size_t SECT = (size_t)BATCH * NPTS * 64;      // 2,097,152
    float*  xt    = ws;
    float*  pt    = ws + SECT;
    float*  zt    = ws + 2 * SECT;
    float*  sq    = ws + 3 * SECT;                       // 32768
    float*  S1    = ws + 3 * SECT + 32768;               // 64
    float*  S2    = S1 + 64;
    int*    idx20 = (int*)(ws + 3 * SECT + 32768 + 128); // 655,360 ints
    float*  uA    = ws + 3 * SECT + 32768 + 128 + 655360;
    // union A (4,194,304 floats = 16.8 MB):
    //   phase 1 (prep..refine): xh | xl | knn32(ushort, B*N*128)
    //   phase 2 (gather..final): tmx | tmn
    ushort* xh    = (ushort*)uA;                         // SECT ushorts
    ushort* xl    = (ushort*)(uA + SECT / 2);            // SECT ushorts
    ushort* knn32 = (ushort*)(uA + SECT);                // B*N*128 ushorts
    float*  tmx   = uA;                                  // SECT floats
    float*  tmn   = uA + SECT;                           // SECT floats
    // total ws use: ~44.7 MB (same footprint as R3/R4)

    hipMemsetAsync(S1, 0, 2 * 64 * sizeof(float), stream);
    k_prep  <<<dim3((BATCH * NPTS) / 256), dim3(256), 0, stream>>>(x, xt, xh, xl, sq);
    k_pz    <<<dim3(BATCH * (NPTS / 64)), dim3(256), 0, stream>>>(xt, W, pt, zt);
    k_knn32 <<<dim3(BATCH * 256 * NPART / 2), dim3(128), 0, stream>>>(xh, xl, sq, knn32);
    k_refine<<<dim3((BATCH * NPTS) / 4), dim3(256), 0, stream>>>(xt, sq, knn32, idx20);
    k_gather<<<dim3(BATCH * (NPTS / 64)), dim3(256), 0, stream>>>(pt, zt, idx20, tmx, tmn, S1, S2);
    k_final <<<dim3(BATCH * (NPTS / 64)), dim3(256), 0, stream>>>(tmx, tmn, S1, S2, gamma, beta, out);
}

// Round 6
// 585.234 us; speedup vs baseline: 1.8937x; 1.8937x over previous
//
#include <hip/hip_runtime.h>
#include <hip/hip_bf16.h>
#include <float.h>

#define BATCH 8
#define CDIM 64
#define NPTS 4096
#define KNN 20
#define KSEL 32
#define BN_EPS 1e-5f
#define NEG_SLOPE 0.2f

typedef __attribute__((ext_vector_type(8))) short short8;
typedef __attribute__((ext_vector_type(4))) float float4v;
typedef unsigned short ushort;
typedef unsigned int uint;

__device__ __forceinline__ ushort f2bf(float f) {
    uint u = __float_as_uint(f);
    u += 0x7FFF + ((u >> 16) & 1);            // round-to-nearest-even
    return (ushort)(u >> 16);
}
__device__ __forceinline__ float bf2f(ushort h) {
    return __uint_as_float(((uint)h) << 16);
}

// cheap cross-lane primitives:
__device__ __forceinline__ float dpp_shr1_f(float x) {   // lane i <- lane i-1 (wave_shr:1)
    int xi = __float_as_int(x);
    return __int_as_float(__builtin_amdgcn_update_dpp(xi, xi, 0x138, 0xF, 0xF, false));
}
__device__ __forceinline__ int dpp_shr1_i(int x) {
    return __builtin_amdgcn_update_dpp(x, x, 0x138, 0xF, 0xF, false);
}
__device__ __forceinline__ float rl_f(float v, int l) {  // readlane (uniform result)
    return __int_as_float(__builtin_amdgcn_readlane(__float_as_int(v), l));
}

// ---------------------------------------------------------------------------
// K1: x [B,C,N] -> xt [B,N,64] fp32, xh/xl [B,N,64] bf16 hi/lo split,
//     sq[b,n] = sum_c x^2 (fp32)
// ---------------------------------------------------------------------------
__global__ void k_prep(const float* __restrict__ x,
                       float* __restrict__ xt,
                       ushort* __restrict__ xh,
                       ushort* __restrict__ xl,
                       float* __restrict__ sq) {
    int gid = blockIdx.x * 256 + threadIdx.x;     // [0, B*N)
    int b = gid >> 12;
    int n = gid & (NPTS - 1);
    const float* xb = x + (size_t)b * CDIM * NPTS + n;
    float acc = 0.f;
    float4* xtv = (float4*)(xt + ((size_t)gid << 6));
    uint2* xhp = (uint2*)(xh + ((size_t)gid << 6));
    uint2* xlp = (uint2*)(xl + ((size_t)gid << 6));
    #pragma unroll
    for (int q = 0; q < 16; ++q) {
        float v[4];
        ushort h[4], l[4];
        #pragma unroll
        for (int j = 0; j < 4; ++j) {
            float t = xb[(q * 4 + j) * NPTS];     // coalesced across n
            v[j] = t;
            acc = fmaf(t, t, acc);
            h[j] = f2bf(t);
            l[j] = f2bf(t - bf2f(h[j]));
        }
        xtv[q] = make_float4(v[0], v[1], v[2], v[3]);
        uint2 ph, pl;
        ph.x = (uint)h[0] | ((uint)h[1] << 16);
        ph.y = (uint)h[2] | ((uint)h[3] << 16);
        pl.x = (uint)l[0] | ((uint)l[1] << 16);
        pl.y = (uint)l[2] | ((uint)l[3] << 16);
        xhp[q] = ph;
        xlp[q] = pl;
    }
    sq[gid] = acc;
}

// ---------------------------------------------------------------------------
// K2: p = W1 @ x, z = (W2-W1) @ x, stored transposed: pt/zt [B,N,64]
// ---------------------------------------------------------------------------
__global__ void k_pz(const float* __restrict__ xt, const float* __restrict__ W,
                     float* __restrict__ pt, float* __restrict__ zt) {
    int b  = blockIdx.x >> 6;
    int n0 = (blockIdx.x & 63) << 6;
    int lane = threadIdx.x & 63;
    int w = threadIdx.x >> 6;
    int n = n0 + lane;
    size_t rowoff = ((size_t)(b * NPTS + n)) << 6;
    const float4* xrow = (const float4*)(xt + rowoff);
    float acc1[16], acc2[16];
    #pragma unroll
    for (int i = 0; i < 16; ++i) { acc1[i] = 0.f; acc2[i] = 0.f; }
    #pragma unroll
    for (int cg = 0; cg < 4; ++cg) {
        float xv[16];
        #pragma unroll
        for (int q = 0; q < 4; ++q) {
            float4 t = xrow[cg * 4 + q];
            xv[q*4] = t.x; xv[q*4+1] = t.y; xv[q*4+2] = t.z; xv[q*4+3] = t.w;
        }
        #pragma unroll
        for (int oi = 0; oi < 16; ++oi) {
            int o = (w << 4) + oi;
            const float* wr = W + o * 128 + cg * 16;
            float a1 = acc1[oi], a2 = acc2[oi];
            #pragma unroll
            for (int j = 0; j < 16; ++j) {
                a1 = fmaf(wr[j],      xv[j], a1);
                a2 = fmaf(wr[64 + j], xv[j], a2);
            }
            acc1[oi] = a1; acc2[oi] = a2;
        }
    }
    float4* pv = (float4*)(pt + rowoff + (w << 4));
    float4* zv = (float4*)(zt + rowoff + (w << 4));
    #pragma unroll
    for (int q = 0; q < 4; ++q) {
        pv[q] = make_float4(acc1[q*4], acc1[q*4+1], acc1[q*4+2], acc1[q*4+3]);
        zv[q] = make_float4(acc2[q*4]   - acc1[q*4],
                            acc2[q*4+1] - acc1[q*4+1],
                            acc2[q*4+2] - acc1[q*4+2],
                            acc2[q*4+3] - acc1[q*4+3]);
    }
}

// ---------------------------------------------------------------------------
// K3: split-bf16 MFMA kNN, single top-32 list per row (minimal insertion
// work), row-split scan for occupancy: block = 512 thr = 8 waves covering 4
// row-groups of 16; wave pair (2 waves) redundantly computes one row-group's
// distance tiles from block-shared LDS staging, each wave scans 8 rows.
// 4096 waves total (4/SIMD).
// ---------------------------------------------------------------------------
__global__ void __launch_bounds__(512) k_knn32(
        const ushort* __restrict__ xh, const ushort* __restrict__ xl,
        const float* __restrict__ sq, ushort* __restrict__ knn32) {
    __shared__ ushort Bh[64][72];     // +8 pad
    __shared__ ushort Bl[64][72];
    __shared__ float dsq[64];
    __shared__ float dwall[8][8][68]; // per-wave 8-row dist tile

    int tid  = threadIdx.x;
    int w    = tid >> 6;              // wave 0..7
    int lane = tid & 63;
    int pair = w >> 1;                // row-group within block 0..3
    int half = w & 1;                 // which 8 rows this wave scans
    int b    = blockIdx.x >> 6;
    int r0   = (((blockIdx.x & 63) << 2) | pair) << 4;   // 16-row group base
    int col = lane & 15;
    int quad = lane >> 4;
    float (*dw)[68] = dwall[w];

    // A fragments (chunk-invariant): row = r0 + col, k = quad*8 + j
    size_t arow = ((size_t)(b * NPTS + r0 + col)) << 6;
    short8 ah0 = *(const short8*)(xh + arow + quad * 8);
    short8 ah1 = *(const short8*)(xh + arow + 32 + quad * 8);
    short8 al0 = *(const short8*)(xl + arow + quad * 8);
    short8 al1 = *(const short8*)(xl + arow + 32 + quad * 8);

    float dl[8]; int il[8]; float tau[8];
    #pragma unroll
    for (int r = 0; r < 8; ++r) { dl[r] = FLT_MAX; il[r] = 0; tau[r] = FLT_MAX; }

    const ushort* xhb = xh + (((size_t)b * NPTS) << 6);
    const ushort* xlb = xl + (((size_t)b * NPTS) << 6);
    const float* sqb = sq + b * NPTS;
    int spt = tid >> 3, seg = tid & 7;    // 64 pts x 8 segs of 8 ushorts

    // prefetch chunk 0
    uint4 vh, vl; float sqpre = 0.f;
    {
        const uint4* gh = (const uint4*)(xhb + ((size_t)spt << 6));
        const uint4* gl = (const uint4*)(xlb + ((size_t)spt << 6));
        vh = gh[seg]; vl = gl[seg];
        if (w == 0) sqpre = sqb[lane];
    }

    for (int chunk = 0; chunk < 64; ++chunk) {
        int m0 = chunk << 6;
        __syncthreads();   // prior-iter B-frag reads done before restage
        *(uint4*)&Bh[spt][seg * 8] = vh;
        *(uint4*)&Bl[spt][seg * 8] = vl;
        if (w == 0) dsq[lane] = sqpre;
        __syncthreads();   // B staged

        if (chunk < 63) {
            int m1 = m0 + 64;
            const uint4* gh = (const uint4*)(xhb + ((size_t)(m1 + spt) << 6));
            const uint4* gl = (const uint4*)(xlb + ((size_t)(m1 + spt) << 6));
            vh = gh[seg]; vl = gl[seg];
            if (w == 0) sqpre = sqb[m1 + lane];
        }

        #pragma unroll
        for (int t = 0; t < 4; ++t) {
            int bp = (t << 4) + col;
            short8 bh0 = *(const short8*)&Bh[bp][quad * 8];
            short8 bh1 = *(const short8*)&Bh[bp][32 + quad * 8];
            short8 bl0 = *(const short8*)&Bl[bp][quad * 8];
            short8 bl1 = *(const short8*)&Bl[bp][32 + quad * 8];
            float4v acc = {0.f, 0.f, 0.f, 0.f};
            acc = __builtin_amdgcn_mfma_f32_16x16x32_bf16(ah0, bh0, acc, 0, 0, 0);
            acc = __builtin_amdgcn_mfma_f32_16x16x32_bf16(ah1, bh1, acc, 0, 0, 0);
            acc = __builtin_amdgcn_mfma_f32_16x16x32_bf16(ah0, bl0, acc, 0, 0, 0);
            acc = __builtin_amdgcn_mfma_f32_16x16x32_bf16(ah1, bl1, acc, 0, 0, 0);
            acc = __builtin_amdgcn_mfma_f32_16x16x32_bf16(al0, bh0, acc, 0, 0, 0);
            acc = __builtin_amdgcn_mfma_f32_16x16x32_bf16(al1, bh1, acc, 0, 0, 0);
            // C/D layout: row = quad*4 + r, cand = t*16 + col.
            // This wave scans rows [8*half, 8*half+8) -> lanes with quad>>1==half
            if ((quad >> 1) == half) {
                #pragma unroll
                for (int r = 0; r < 4; ++r)
                    dw[((quad & 1) << 2) + r][(t << 4) + col] = acc[r];
            }
        }

        // wave-private transpose: lane = candidate
        float sv = dsq[lane];
        float dvals[8];
        #pragma unroll
        for (int r = 0; r < 8; ++r)
            dvals[r] = fmaf(-2.f, dw[r][lane], sv);

        #pragma unroll
        for (int r = 0; r < 8; ++r) {
            float d = dvals[r];
            unsigned long long mask = __ballot(d < tau[r]);
            while (mask) {
                int s = __ffsll((long long)mask) - 1;
                mask &= mask - 1;
                float ds = rl_f(d, s);
                if (!(ds < tau[r])) continue;            // stale bit (uniform)
                unsigned long long gt = __ballot(ds < dl[r]);
                int pos = __ffsll((long long)gt) - 1;    // insertion point <= 31
                float pd = dpp_shr1_f(dl[r]);
                int   pi = dpp_shr1_i(il[r]);
                if (lane >= pos && lane < KSEL) {
                    dl[r] = (lane == pos) ? ds : pd;
                    il[r] = (lane == pos) ? (m0 + s) : pi;
                }
                tau[r] = rl_f(dl[r], KSEL - 1);
            }
        }
    }
    #pragma unroll
    for (int r = 0; r < 8; ++r)
        if (lane < KSEL)
            knn32[(((size_t)(b * NPTS + r0 + (half << 3) + r)) << 5) + lane] =
                (ushort)il[r];
}

// ---------------------------------------------------------------------------
// K3b: exact fp32 refinement — one wave per row; lanes (mod 32) hold the 32
// candidates, recompute exact fp32 distances, rank lexicographically
// (dist, idx) to match np's lower-index-first tie rule, emit top-20 set.
// ---------------------------------------------------------------------------
__global__ void __launch_bounds__(256) k_refine(
        const float* __restrict__ xt, const float* __restrict__ sq,
        const ushort* __restrict__ knn32, int* __restrict__ idx20) {
    int wid = (blockIdx.x << 2) + (threadIdx.x >> 6);  // row id [0, B*N)
    int lane = threadIdx.x & 63;
    int b = wid >> 12;
    int cand = knn32[((size_t)wid << 5) + (lane & (KSEL - 1))];
    const float4* xc = (const float4*)(xt + ((size_t)(b * NPTS + cand) << 6));
    const float4* xr = (const float4*)(xt + ((size_t)wid << 6));
    float acc = 0.f;
    #pragma unroll
    for (int q = 0; q < 16; ++q) {
        float4 a = xr[q], c = xc[q];
        acc = fmaf(a.x, c.x, acc); acc = fmaf(a.y, c.y, acc);
        acc = fmaf(a.z, c.z, acc); acc = fmaf(a.w, c.w, acc);
    }
    float d = fmaf(-2.f, acc, sq[b * NPTS + cand]);
    int rank = 0;
    #pragma unroll
    for (int j = 0; j < KSEL; ++j) {
        float dj = __shfl(d, j);
        int   cj = __shfl(cand, j);
        rank += ((dj < d) || (dj == d && cj < cand)) ? 1 : 0;
    }
    if (lane < KSEL && rank < KNN)
        idx20[(size_t)wid * KNN + rank] = cand;
}

// ---------------------------------------------------------------------------
// K4: gather p columns per neighbor; per-(b,n) max/min/sum/sumsq over k;
// write tmax/tmin = (max/min_k p[idx]) + z; accumulate channel sums.
// ---------------------------------------------------------------------------
__global__ void k_gather(const float* __restrict__ pt, const float* __restrict__ zt,
                         const int* __restrict__ idxin,
                         float* __restrict__ tmax, float* __restrict__ tmin,
                         float* __restrict__ S1, float* __restrict__ S2) {
    __shared__ float red1[4][64];
    __shared__ float red2[4][64];
    int b  = blockIdx.x >> 6;
    int n0 = (blockIdx.x & 63) << 6;
    int lane = threadIdx.x & 63;
    int w = threadIdx.x >> 6;
    float cs1 = 0.f, cs2 = 0.f;
    for (int i = 0; i < 16; ++i) {
        int n = n0 + (w << 4) + i;
        int base = b * NPTS + n;
        int ibase = __builtin_amdgcn_readfirstlane(base * KNN);
        const int* ip = idxin + ibase;
        float mx = -FLT_MAX, mn = FLT_MAX, s1 = 0.f, s2 = 0.f;
        #pragma unroll
        for (int k = 0; k < KNN; ++k) {
            int colp = ip[k];                              // SGPR
            float v = pt[(((size_t)(b * NPTS + colp)) << 6) + lane]; // coalesced
            mx = fmaxf(mx, v); mn = fminf(mn, v);
            s1 += v; s2 = fmaf(v, v, s2);
        }
        float z = zt[(((size_t)base) << 6) + lane];
        tmax[(((size_t)base) << 6) + lane] = mx + z;
        tmin[(((size_t)base) << 6) + lane] = mn + z;
        cs1 += s1 + (float)KNN * z;
        cs2 += s2 + 2.f * z * s1 + (float)KNN * z * z;
    }
    red1[w][lane] = cs1;
    red2[w][lane] = cs2;
    __syncthreads();
    if (threadIdx.x < 64) {
        float t1 = red1[0][lane] + red1[1][lane] + red1[2][lane] + red1[3][lane];
        float t2 = red2[0][lane] + red2[1][lane] + red2[2][lane] + red2[3][lane];
        atomicAdd(&S1[lane], t1);
        atomicAdd(&S2[lane], t2);
    }
}

// ---------------------------------------------------------------------------
// K5: finalize BN stats, affine + LeakyReLU, transpose to out [B,64,N].
// ---------------------------------------------------------------------------
__global__ void k_final(const float* __restrict__ tmax, const float* __restrict__ tmin,
                        const float* __restrict__ S1, const float* __restrict__ S2,
                        const float* __restrict__ gamma, const float* __restrict__ beta,
                        float* __restrict__ out) {
    __shared__ float smx[64][65];
    __shared__ float smn[64][65];
    int b  = blockIdx.x >> 6;
    int n0 = (blockIdx.x & 63) << 6;
    int lane = threadIdx.x & 63;
    int w = threadIdx.x >> 6;
    #pragma unroll
    for (int i = 0; i < 16; ++i) {
        int nl = (i << 2) + w;
        size_t off = (((size_t)(b * NPTS + n0 + nl)) << 6) + lane;
        smx[nl][lane] = tmax[off];
        smn[nl][lane] = tmin[off];
    }
    __syncthreads();
    const float inv_cnt = 1.0f / ((float)BATCH * NPTS * KNN);
    #pragma unroll
    for (int i = 0; i < 16; ++i) {
        int o = (i << 2) + w;
        float s1 = S1[o], s2 = S2[o];
        float mean = s1 * inv_cnt;
        float var = fmaf(-mean, mean, s2 * inv_cnt);
        float rs = rsqrtf(var + BN_EPS);
        float sc = gamma[o] * rs;
        float sh = beta[o] - mean * sc;
        float tv = (sc >= 0.f) ? smx[lane][o] : smn[lane][o];
        float y = fmaf(tv, sc, sh);
        y = (y >= 0.f) ? y : NEG_SLOPE * y;
        out[((size_t)(b * 64 + o)) * NPTS + n0 + lane] = y;
    }
}

// ---------------------------------------------------------------------------
extern "C" void kernel_launch(void* const* d_in, const int* in_sizes, int n_in,
                              void* d_out, int out_size, void* d_ws, size_t ws_size,
                              hipStream_t stream) {
    const float* x     = (const float*)d_in[0];   // [8,64,4096]
    const float* W     = (const float*)d_in[1];   // [64,128]
    const float* gamma = (const float*)d_in[2];   // [64]
    const float* beta  = (const float*)d_in[3];   // [64]
    float* out = (float*)d_out;                   // [8,64,4096]

    float* ws = (float*)d_ws;
    const size_t SECT = (size_t)BATCH * NPTS * 64;      // 2,097,152
    float*  xt    = ws;
    float*  pt    = ws + SECT;
    float*  zt    = ws + 2 * SECT;
    float*  sq    = ws + 3 * SECT;                       // 32768
    float*  S1    = ws + 3 * SECT + 32768;               // 64
    float*  S2    = S1 + 64;
    int*    idx20 = (int*)(ws + 3 * SECT + 32768 + 128); // 655,360 ints
    float*  uA    = ws + 3 * SECT + 32768 + 128 + 655360;
    // union A:
    //   phase 1 (prep..refine): xh | xl | knn32(ushort, B*N*32)
    //   phase 2 (gather..final): tmx | tmn
    ushort* xh    = (ushort*)uA;                         // SECT ushorts
    ushort* xl    = (ushort*)(uA + SECT / 2);            // SECT ushorts
    ushort* knn32 = (ushort*)(uA + SECT);                // B*N*32 ushorts
    float*  tmx   = uA;                                  // SECT floats
    float*  tmn   = uA + SECT;                           // SECT floats
    // total ws use: ~44.7 MB

    hipMemsetAsync(S1, 0, 2 * 64 * sizeof(float), stream);
    k_prep  <<<dim3((BATCH * NPTS) / 256), dim3(256), 0, stream>>>(x, xt, xh, xl, sq);
    k_pz    <<<dim3(BATCH * (NPTS / 64)), dim3(256), 0, stream>>>(xt, W, pt, zt);
    k_knn32 <<<dim3(512), dim3(512), 0, stream>>>(xh, xl, sq, knn32);
    k_refine<<<dim3((BATCH * NPTS) / 4), dim3(256), 0, stream>>>(xt, sq, knn32, idx20);
    k_gather<<<dim3(BATCH * (NPTS / 64)), dim3(256), 0, stream>>>(pt, zt, idx20, tmx, tmn, S1, S2);
    k_final <<<dim3(BATCH * (NPTS / 64)), dim3(256), 0, stream>>>(tmx, tmn, S1, S2, gamma, beta, out);
}

// Round 7
// 540.042 us; speedup vs baseline: 2.0521x; 1.0837x over previous
//
#include <hip/hip_runtime.h>
#include <hip/hip_bf16.h>
#include <float.h>

#define BATCH 8
#define CDIM 64
#define NPTS 4096
#define KNN 20
#define KSEL 24
#define BN_EPS 1e-5f
#define NEG_SLOPE 0.2f

typedef __attribute__((ext_vector_type(8))) short short8;
typedef __attribute__((ext_vector_type(4))) float float4v;
typedef unsigned short ushort;
typedef unsigned int uint;

__device__ __forceinline__ ushort f2bf(float f) {
    uint u = __float_as_uint(f);
    u += 0x7FFF + ((u >> 16) & 1);            // round-to-nearest-even
    return (ushort)(u >> 16);
}
__device__ __forceinline__ float bf2f(ushort h) {
    return __uint_as_float(((uint)h) << 16);
}

// cheap cross-lane primitives:
__device__ __forceinline__ float dpp_shr1_f(float x) {   // lane i <- lane i-1 (wave_shr:1)
    int xi = __float_as_int(x);
    return __int_as_float(__builtin_amdgcn_update_dpp(xi, xi, 0x138, 0xF, 0xF, false));
}
__device__ __forceinline__ int dpp_shr1_i(int x) {
    return __builtin_amdgcn_update_dpp(x, x, 0x138, 0xF, 0xF, false);
}
__device__ __forceinline__ float rl_f(float v, int l) {  // readlane (uniform result)
    return __int_as_float(__builtin_amdgcn_readlane(__float_as_int(v), l));
}

// ---------------------------------------------------------------------------
// K1 (fused prep+pz): x [B,C,N] -> xt [B,N,64] fp32, xh/xl bf16 hi/lo split,
// sq[b,n]; and p = W1@x, z = (W2-W1)@x stored transposed pt/zt [B,N,64].
// Each thread holds its full 64-dim row in registers; W reads are
// thread-uniform (scalar loads).
// ---------------------------------------------------------------------------
__global__ void k_prep(const float* __restrict__ x,
                       const float* __restrict__ W,
                       float* __restrict__ xt,
                       ushort* __restrict__ xh,
                       ushort* __restrict__ xl,
                       float* __restrict__ sq,
                       float* __restrict__ pt,
                       float* __restrict__ zt) {
    int gid = blockIdx.x * 256 + threadIdx.x;     // [0, B*N)
    int b = gid >> 12;
    int n = gid & (NPTS - 1);
    const float* xb = x + (size_t)b * CDIM * NPTS + n;
    float xv[64];
    float acc = 0.f;
    #pragma unroll
    for (int c = 0; c < 64; ++c) {
        xv[c] = xb[c * NPTS];                     // coalesced across n
        acc = fmaf(xv[c], xv[c], acc);
    }
    sq[gid] = acc;
    float4* xtv = (float4*)(xt + ((size_t)gid << 6));
    uint2* xhp = (uint2*)(xh + ((size_t)gid << 6));
    uint2* xlp = (uint2*)(xl + ((size_t)gid << 6));
    #pragma unroll
    for (int q = 0; q < 16; ++q) {
        xtv[q] = make_float4(xv[q*4], xv[q*4+1], xv[q*4+2], xv[q*4+3]);
        ushort h[4], l[4];
        #pragma unroll
        for (int j = 0; j < 4; ++j) {
            h[j] = f2bf(xv[q*4+j]);
            l[j] = f2bf(xv[q*4+j] - bf2f(h[j]));
        }
        uint2 ph, pl;
        ph.x = (uint)h[0] | ((uint)h[1] << 16);
        ph.y = (uint)h[2] | ((uint)h[3] << 16);
        pl.x = (uint)l[0] | ((uint)l[1] << 16);
        pl.y = (uint)l[2] | ((uint)l[3] << 16);
        xhp[q] = ph;
        xlp[q] = pl;
    }
    // p/z: 64 outputs, W row-major [64][128]
    float4* pv = (float4*)(pt + ((size_t)gid << 6));
    float4* zv = (float4*)(zt + ((size_t)gid << 6));
    for (int og = 0; og < 16; ++og) {
        float pr[4], zr[4];
        #pragma unroll
        for (int oi = 0; oi < 4; ++oi) {
            const float* wr = W + (og * 4 + oi) * 128;   // uniform -> scalar
            float a1 = 0.f, a2 = 0.f;
            #pragma unroll
            for (int c = 0; c < 64; ++c) {
                a1 = fmaf(wr[c],      xv[c], a1);
                a2 = fmaf(wr[64 + c], xv[c], a2);
            }
            pr[oi] = a1; zr[oi] = a2 - a1;
        }
        pv[og] = make_float4(pr[0], pr[1], pr[2], pr[3]);
        zv[og] = make_float4(zr[0], zr[1], zr[2], zr[3]);
    }
}

// ---------------------------------------------------------------------------
// K2: split-bf16 MFMA kNN, single top-24 list per row.
// Block = 512 thr = 8 waves over 2 row-groups of 16 rows. Within a group,
// wave t computes ONE 16x16 tile (6 MFMAs, cands [16t,16t+16)) into the
// group-shared dw tile; barrier; wave t scans rows [4t,4t+4) over all 64
// candidates. Non-redundant MFMA, 8192 waves, grid 1024 -> 4 blocks/CU.
// ---------------------------------------------------------------------------
__global__ void __launch_bounds__(512) k_knn(
        const ushort* __restrict__ xh, const ushort* __restrict__ xl,
        const float* __restrict__ sq, ushort* __restrict__ knn24) {
    __shared__ ushort Bh[64][72];     // +8 pad
    __shared__ ushort Bl[64][72];
    __shared__ float dsq[64];
    __shared__ float dw[2][16][68];   // per-group dist tile, padded

    int tid  = threadIdx.x;
    int wv   = tid >> 6;              // wave 0..7
    int lane = tid & 63;
    int g    = wv >> 2;               // row-group 0..1
    int t    = wv & 3;                // tile / row-quarter
    int b    = blockIdx.x >> 7;       // 128 blocks per batch
    int r0   = ((blockIdx.x & 127) << 5) + (g << 4);   // group base row
    int col  = lane & 15;
    int quad = lane >> 4;

    // A fragments (chunk-invariant): row = r0 + col, k = quad*8 + j
    size_t arow = ((size_t)(b * NPTS + r0 + col)) << 6;
    short8 ah0 = *(const short8*)(xh + arow + quad * 8);
    short8 ah1 = *(const short8*)(xh + arow + 32 + quad * 8);
    short8 al0 = *(const short8*)(xl + arow + quad * 8);
    short8 al1 = *(const short8*)(xl + arow + 32 + quad * 8);

    float dl[4]; int il[4]; float tau[4];
    #pragma unroll
    for (int r = 0; r < 4; ++r) { dl[r] = FLT_MAX; il[r] = 0; tau[r] = FLT_MAX; }

    const ushort* xhb = xh + (((size_t)b * NPTS) << 6);
    const ushort* xlb = xl + (((size_t)b * NPTS) << 6);
    const float* sqb = sq + b * NPTS;
    int spt = tid >> 3, seg = tid & 7;    // 64 pts x 8 segs of 8 ushorts

    // prefetch chunk 0
    uint4 vh, vl; float sqpre = 0.f;
    {
        const uint4* gh = (const uint4*)(xhb + ((size_t)spt << 6));
        const uint4* gl = (const uint4*)(xlb + ((size_t)spt << 6));
        vh = gh[seg]; vl = gl[seg];
        if (wv == 0) sqpre = sqb[lane];
    }

    for (int chunk = 0; chunk < 64; ++chunk) {
        int m0 = chunk << 6;
        __syncthreads();   // prior-iter dw reads + B-frag reads done
        *(uint4*)&Bh[spt][seg * 8] = vh;
        *(uint4*)&Bl[spt][seg * 8] = vl;
        if (wv == 0) dsq[lane] = sqpre;
        __syncthreads();   // B staged

        if (chunk < 63) {
            int m1 = m0 + 64;
            const uint4* gh = (const uint4*)(xhb + ((size_t)(m1 + spt) << 6));
            const uint4* gl = (const uint4*)(xlb + ((size_t)(m1 + spt) << 6));
            vh = gh[seg]; vl = gl[seg];
            if (wv == 0) sqpre = sqb[m1 + lane];
        }

        // this wave's single tile: cands [16t, 16t+16), all 16 rows
        {
            int bp = (t << 4) + col;
            short8 bh0 = *(const short8*)&Bh[bp][quad * 8];
            short8 bh1 = *(const short8*)&Bh[bp][32 + quad * 8];
            short8 bl0 = *(const short8*)&Bl[bp][quad * 8];
            short8 bl1 = *(const short8*)&Bl[bp][32 + quad * 8];
            float4v acc = {0.f, 0.f, 0.f, 0.f};
            acc = __builtin_amdgcn_mfma_f32_16x16x32_bf16(ah0, bh0, acc, 0, 0, 0);
            acc = __builtin_amdgcn_mfma_f32_16x16x32_bf16(ah1, bh1, acc, 0, 0, 0);
            acc = __builtin_amdgcn_mfma_f32_16x16x32_bf16(ah0, bl0, acc, 0, 0, 0);
            acc = __builtin_amdgcn_mfma_f32_16x16x32_bf16(ah1, bl1, acc, 0, 0, 0);
            acc = __builtin_amdgcn_mfma_f32_16x16x32_bf16(al0, bh0, acc, 0, 0, 0);
            acc = __builtin_amdgcn_mfma_f32_16x16x32_bf16(al1, bh1, acc, 0, 0, 0);
            // C/D: row = quad*4 + r, cand = t*16 + col
            #pragma unroll
            for (int r = 0; r < 4; ++r)
                dw[g][(quad << 2) + r][(t << 4) + col] = acc[r];
        }
        __syncthreads();   // dw complete for both groups

        // scan rows [4t, 4t+4); lane = candidate
        float sv = dsq[lane];
        float dvals[4];
        #pragma unroll
        for (int r = 0; r < 4; ++r)
            dvals[r] = fmaf(-2.f, dw[g][(t << 2) + r][lane], sv);

        #pragma unroll
        for (int r = 0; r < 4; ++r) {
            float d = dvals[r];
            unsigned long long mask = __ballot(d < tau[r]);
            while (mask) {
                int s = __ffsll((long long)mask) - 1;
                mask &= mask - 1;
                float ds = rl_f(d, s);
                if (!(ds < tau[r])) continue;            // stale bit (uniform)
                unsigned long long gt = __ballot(ds < dl[r]);
                int pos = __ffsll((long long)gt) - 1;    // insertion point < KSEL
                float pd = dpp_shr1_f(dl[r]);
                int   pi = dpp_shr1_i(il[r]);
                if (lane >= pos && lane < KSEL) {
                    dl[r] = (lane == pos) ? ds : pd;
                    il[r] = (lane == pos) ? (m0 + s) : pi;
                }
                tau[r] = rl_f(dl[r], KSEL - 1);
            }
        }
    }
    #pragma unroll
    for (int r = 0; r < 4; ++r)
        if (lane < KSEL)
            knn24[(size_t)(b * NPTS + r0 + (t << 2) + r) * KSEL + lane] =
                (ushort)il[r];
}

// ---------------------------------------------------------------------------
// K3: exact fp32 refinement — one wave per row; lanes 0..23 hold candidates,
// recompute exact fp32 distances, rank lexicographically (dist, idx) to
// match np's lower-index-first tie rule, emit top-20 set.
// ---------------------------------------------------------------------------
__global__ void __launch_bounds__(256) k_refine(
        const float* __restrict__ xt, const float* __restrict__ sq,
        const ushort* __restrict__ knn24, int* __restrict__ idx20) {
    int wid = (blockIdx.x << 2) + (threadIdx.x >> 6);  // row id [0, B*N)
    int lane = threadIdx.x & 63;
    int b = wid >> 12;
    int cl = (lane < KSEL) ? lane : (KSEL - 1);
    int cand = knn24[(size_t)wid * KSEL + cl];
    const float4* xc = (const float4*)(xt + ((size_t)(b * NPTS + cand) << 6));
    const float4* xr = (const float4*)(xt + ((size_t)wid << 6));
    float acc = 0.f;
    #pragma unroll
    for (int q = 0; q < 16; ++q) {
        float4 a = xr[q], c = xc[q];
        acc = fmaf(a.x, c.x, acc); acc = fmaf(a.y, c.y, acc);
        acc = fmaf(a.z, c.z, acc); acc = fmaf(a.w, c.w, acc);
    }
    float d = fmaf(-2.f, acc, sq[b * NPTS + cand]);
    int rank = 0;
    #pragma unroll
    for (int j = 0; j < KSEL; ++j) {
        float dj = __shfl(d, j);
        int   cj = __shfl(cand, j);
        rank += ((dj < d) || (dj == d && cj < cand)) ? 1 : 0;
    }
    if (lane < KSEL && rank < KNN)
        idx20[(size_t)wid * KNN + rank] = cand;
}

// ---------------------------------------------------------------------------
// K4: gather p columns per neighbor; per-(b,n) max/min/sum/sumsq over k;
// write tmax/tmin = (max/min_k p[idx]) + z; accumulate channel sums.
// ---------------------------------------------------------------------------
__global__ void k_gather(const float* __restrict__ pt, const float* __restrict__ zt,
                         const int* __restrict__ idxin,
                         float* __restrict__ tmax, float* __restrict__ tmin,
                         float* __restrict__ S1, float* __restrict__ S2) {
    __shared__ float red1[4][64];
    __shared__ float red2[4][64];
    int b  = blockIdx.x >> 6;
    int n0 = (blockIdx.x & 63) << 6;
    int lane = threadIdx.x & 63;
    int w = threadIdx.x >> 6;
    float cs1 = 0.f, cs2 = 0.f;
    for (int i = 0; i < 16; ++i) {
        int n = n0 + (w << 4) + i;
        int base = b * NPTS + n;
        int ibase = __builtin_amdgcn_readfirstlane(base * KNN);
        const int* ip = idxin + ibase;
        float mx = -FLT_MAX, mn = FLT_MAX, s1 = 0.f, s2 = 0.f;
        #pragma unroll
        for (int k = 0; k < KNN; ++k) {
            int colp = ip[k];                              // SGPR
            float v = pt[(((size_t)(b * NPTS + colp)) << 6) + lane]; // coalesced
            mx = fmaxf(mx, v); mn = fminf(mn, v);
            s1 += v; s2 = fmaf(v, v, s2);
        }
        float z = zt[(((size_t)base) << 6) + lane];
        tmax[(((size_t)base) << 6) + lane] = mx + z;
        tmin[(((size_t)base) << 6) + lane] = mn + z;
        cs1 += s1 + (float)KNN * z;
        cs2 += s2 + 2.f * z * s1 + (float)KNN * z * z;
    }
    red1[w][lane] = cs1;
    red2[w][lane] = cs2;
    __syncthreads();
    if (threadIdx.x < 64) {
        float t1 = red1[0][lane] + red1[1][lane] + red1[2][lane] + red1[3][lane];
        float t2 = red2[0][lane] + red2[1][lane] + red2[2][lane] + red2[3][lane];
        atomicAdd(&S1[lane], t1);
        atomicAdd(&S2[lane], t2);
    }
}

// ---------------------------------------------------------------------------
// K5: finalize BN stats, affine + LeakyReLU, transpose to out [B,64,N].
// ---------------------------------------------------------------------------
__global__ void k_final(const float* __restrict__ tmax, const float* __restrict__ tmin,
                        const float* __restrict__ S1, const float* __restrict__ S2,
                        const float* __restrict__ gamma, const float* __restrict__ beta,
                        float* __restrict__ out) {
    __shared__ float smx[64][65];
    __shared__ float smn[64][65];
    int b  = blockIdx.x >> 6;
    int n0 = (blockIdx.x & 63) << 6;
    int lane = threadIdx.x & 63;
    int w = threadIdx.x >> 6;
    #pragma unroll
    for (int i = 0; i < 16; ++i) {
        int nl = (i << 2) + w;
        size_t off = (((size_t)(b * NPTS + n0 + nl)) << 6) + lane;
        smx[nl][lane] = tmax[off];
        smn[nl][lane] = tmin[off];
    }
    __syncthreads();
    const float inv_cnt = 1.0f / ((float)BATCH * NPTS * KNN);
    #pragma unroll
    for (int i = 0; i < 16; ++i) {
        int o = (i << 2) + w;
        float s1 = S1[o], s2 = S2[o];
        float mean = s1 * inv_cnt;
        float var = fmaf(-mean, mean, s2 * inv_cnt);
        float rs = rsqrtf(var + BN_EPS);
        float sc = gamma[o] * rs;
        float sh = beta[o] - mean * sc;
        float tv = (sc >= 0.f) ? smx[lane][o] : smn[lane][o];
        float y = fmaf(tv, sc, sh);
        y = (y >= 0.f) ? y : NEG_SLOPE * y;
        out[((size_t)(b * 64 + o)) * NPTS + n0 + lane] = y;
    }
}

// ---------------------------------------------------------------------------
extern "C" void kernel_launch(void* const* d_in, const int* in_sizes, int n_in,
                              void* d_out, int out_size, void* d_ws, size_t ws_size,
                              hipStream_t stream) {
    const float* x     = (const float*)d_in[0];   // [8,64,4096]
    const float* W     = (const float*)d_in[1];   // [64,128]
    const float* gamma = (const float*)d_in[2];   // [64]
    const float* beta  = (const float*)d_in[3];   // [64]
    float* out = (float*)d_out;                   // [8,64,4096]

    float* ws = (float*)d_ws;
    const size_t SECT = (size_t)BATCH * NPTS * 64;      // 2,097,152
    float*  xt    = ws;
    float*  pt    = ws + SECT;
    float*  zt    = ws + 2 * SECT;
    float*  sq    = ws + 3 * SECT;                       // 32768
    float*  S1    = ws + 3 * SECT + 32768;               // 64
    float*  S2    = S1 + 64;
    int*    idx20 = (int*)(ws + 3 * SECT + 32768 + 128); // 655,360 ints
    float*  uA    = ws + 3 * SECT + 32768 + 128 + 655360;
    // union A:
    //   phase 1 (prep..refine): xh | xl | knn24(ushort, B*N*24)
    //   phase 2 (gather..final): tmx | tmn
    ushort* xh    = (ushort*)uA;                         // SECT ushorts
    ushort* xl    = (ushort*)(uA + SECT / 2);            // SECT ushorts
    ushort* knn24 = (ushort*)(uA + SECT);                // B*N*24 ushorts
    float*  tmx   = uA;                                  // SECT floats
    float*  tmn   = uA + SECT;                           // SECT floats
    // total ws use: ~44.7 MB

    hipMemsetAsync(S1, 0, 2 * 64 * sizeof(float), stream);
    k_prep  <<<dim3((BATCH * NPTS) / 256), dim3(256), 0, stream>>>(x, W, xt, xh, xl, sq, pt, zt);
    k_knn   <<<dim3(1024), dim3(512), 0, stream>>>(xh, xl, sq, knn24);
    k_refine<<<dim3((BATCH * NPTS) / 4), dim3(256), 0, stream>>>(xt, sq, knn24, idx20);
    k_gather<<<dim3(BATCH * (NPTS / 64)), dim3(256), 0, stream>>>(pt, zt, idx20, tmx, tmn, S1, S2);
    k_final <<<dim3(BATCH * (NPTS / 64)), dim3(256), 0, stream>>>(tmx, tmn, S1, S2, gamma, beta, out);
}

// Round 8
// 528.797 us; speedup vs baseline: 2.0958x; 1.0213x over previous
//
#include <hip/hip_runtime.h>
#include <hip/hip_bf16.h>
#include <float.h>

#define BATCH 8
#define CDIM 64
#define NPTS 4096
#define KNN 20
#define KSEL 32
#define BUFCAP 96
#define BN_EPS 1e-5f
#define NEG_SLOPE 0.2f

typedef __attribute__((ext_vector_type(8))) short short8;
typedef __attribute__((ext_vector_type(4))) float float4v;
typedef unsigned short ushort;
typedef unsigned int uint;

__device__ __forceinline__ ushort f2bf(float f) {
    uint u = __float_as_uint(f);
    u += 0x7FFF + ((u >> 16) & 1);            // round-to-nearest-even
    return (ushort)(u >> 16);
}
__device__ __forceinline__ float bf2f(ushort h) {
    return __uint_as_float(((uint)h) << 16);
}
__device__ __forceinline__ int mbcnt64(unsigned long long m) {
    int c = __builtin_amdgcn_mbcnt_lo((uint)m, 0);
    return __builtin_amdgcn_mbcnt_hi((uint)(m >> 32), c);
}

// Find 33rd-smallest key in buf[0..cnt), compact keys < K33 to front,
// set cnt to the kept count (==32 when cnt>=33, else keeps all). Returns K33.
__device__ __forceinline__ uint select33_truncate(uint* __restrict__ buf,
                                                  int& cnt, int lane) {
    uint e0 = 0xFFFFFFFFu, e1 = 0xFFFFFFFFu;
    if (lane < cnt) e0 = buf[lane];
    if (64 + lane < cnt) e1 = buf[64 + lane];
    uint p = 0;
    for (int bit = 31; bit >= 0; --bit) {
        uint t = p | (1u << bit);
        unsigned long long mA = __ballot(e0 < t);
        unsigned long long mB = __ballot(e1 < t);
        if (__popcll(mA) + __popcll(mB) < 33) p = t;   // uniform
    }
    unsigned long long mA = __ballot(e0 < p);
    unsigned long long mB = __ballot(e1 < p);
    int pA = __popcll(mA);
    int r0 = mbcnt64(mA);
    int r1 = pA + mbcnt64(mB);
    if (e0 < p) buf[r0] = e0;
    if (e1 < p) buf[r1] = e1;
    cnt = pA + __popcll(mB);
    return p;
}

// ---------------------------------------------------------------------------
// K1 (fused prep+pz): x [B,C,N] -> xt [B,N,64] fp32, xh/xl bf16 hi/lo split,
// sq[b,n]; and p = W1@x, z = (W2-W1)@x stored transposed pt/zt [B,N,64].
// ---------------------------------------------------------------------------
__global__ void k_prep(const float* __restrict__ x,
                       const float* __restrict__ W,
                       float* __restrict__ xt,
                       ushort* __restrict__ xh,
                       ushort* __restrict__ xl,
                       float* __restrict__ sq,
                       float* __restrict__ pt,
                       float* __restrict__ zt) {
    int gid = blockIdx.x * 256 + threadIdx.x;     // [0, B*N)
    int b = gid >> 12;
    int n = gid & (NPTS - 1);
    const float* xb = x + (size_t)b * CDIM * NPTS + n;
    float xv[64];
    float acc = 0.f;
    #pragma unroll
    for (int c = 0; c < 64; ++c) {
        xv[c] = xb[c * NPTS];                     // coalesced across n
        acc = fmaf(xv[c], xv[c], acc);
    }
    sq[gid] = acc;
    float4* xtv = (float4*)(xt + ((size_t)gid << 6));
    uint2* xhp = (uint2*)(xh + ((size_t)gid << 6));
    uint2* xlp = (uint2*)(xl + ((size_t)gid << 6));
    #pragma unroll
    for (int q = 0; q < 16; ++q) {
        xtv[q] = make_float4(xv[q*4], xv[q*4+1], xv[q*4+2], xv[q*4+3]);
        ushort h[4], l[4];
        #pragma unroll
        for (int j = 0; j < 4; ++j) {
            h[j] = f2bf(xv[q*4+j]);
            l[j] = f2bf(xv[q*4+j] - bf2f(h[j]));
        }
        uint2 ph, pl;
        ph.x = (uint)h[0] | ((uint)h[1] << 16);
        ph.y = (uint)h[2] | ((uint)h[3] << 16);
        pl.x = (uint)l[0] | ((uint)l[1] << 16);
        pl.y = (uint)l[2] | ((uint)l[3] << 16);
        xhp[q] = ph;
        xlp[q] = pl;
    }
    float4* pv = (float4*)(pt + ((size_t)gid << 6));
    float4* zv = (float4*)(zt + ((size_t)gid << 6));
    for (int og = 0; og < 16; ++og) {
        float pr[4], zr[4];
        #pragma unroll
        for (int oi = 0; oi < 4; ++oi) {
            const float* wr = W + (og * 4 + oi) * 128;   // uniform -> scalar
            float a1 = 0.f, a2 = 0.f;
            #pragma unroll
            for (int c = 0; c < 64; ++c) {
                a1 = fmaf(wr[c],      xv[c], a1);
                a2 = fmaf(wr[64 + c], xv[c], a2);
            }
            pr[oi] = a1; zr[oi] = a2 - a1;
        }
        pv[og] = make_float4(pr[0], pr[1], pr[2], pr[3]);
        zv[og] = make_float4(zr[0], zr[1], zr[2], zr[3]);
    }
}

// ---------------------------------------------------------------------------
// K2: split-bf16 MFMA kNN. Block = 8 waves over 2 row-groups of 16 rows;
// wave t computes ONE 16x16 tile into the group dw, then scans rows
// [4t,4t+4). Scan = packed-key (20-bit dist | 12-bit idx) mbcnt-append into
// a 96-entry LDS buffer per row; rare ballot-bisection select-33 tightens
// tau and truncates to 32. No per-event cross-lane chains.
// ---------------------------------------------------------------------------
__global__ void __launch_bounds__(512) k_knn(
        const ushort* __restrict__ xh, const ushort* __restrict__ xl,
        const float* __restrict__ sq, ushort* __restrict__ knn32) {
    __shared__ ushort Bh[64][72];     // +8 pad
    __shared__ ushort Bl[64][72];
    __shared__ float dsq[64];
    __shared__ float dw[2][16][68];   // per-group dist tile, padded
    __shared__ uint rowbuf[32 * BUFCAP];   // 8 waves x 4 rows x 96

    int tid  = threadIdx.x;
    int wv   = tid >> 6;              // wave 0..7
    int lane = tid & 63;
    int g    = wv >> 2;               // row-group 0..1
    int t    = wv & 3;                // tile / row-quarter
    int b    = blockIdx.x >> 7;       // 128 blocks per batch
    int r0   = ((blockIdx.x & 127) << 5) + (g << 4);   // group base row
    int col  = lane & 15;
    int quad = lane >> 4;

    // A fragments (chunk-invariant): row = r0 + col, k = quad*8 + j
    size_t arow = ((size_t)(b * NPTS + r0 + col)) << 6;
    short8 ah0 = *(const short8*)(xh + arow + quad * 8);
    short8 ah1 = *(const short8*)(xh + arow + 32 + quad * 8);
    short8 al0 = *(const short8*)(xl + arow + quad * 8);
    short8 al1 = *(const short8*)(xl + arow + 32 + quad * 8);

    const ushort* xhb = xh + (((size_t)b * NPTS) << 6);
    const ushort* xlb = xl + (((size_t)b * NPTS) << 6);
    const float* sqb = sq + b * NPTS;
    int spt = tid >> 3, seg = tid & 7;    // 64 pts x 8 segs of 8 ushorts

    uint tau[4];
    int cnt[4];
    float sqr[4];
    uint* buf[4];
    #pragma unroll
    for (int r = 0; r < 4; ++r) {
        tau[r] = 0xFFFFFFFFu; cnt[r] = 0;
        sqr[r] = sqb[r0 + (t << 2) + r];
        buf[r] = rowbuf + ((wv << 2) + r) * BUFCAP;
    }

    // prefetch chunk 0
    uint4 vh, vl; float sqpre = 0.f;
    {
        const uint4* gh = (const uint4*)(xhb + ((size_t)spt << 6));
        const uint4* gl = (const uint4*)(xlb + ((size_t)spt << 6));
        vh = gh[seg]; vl = gl[seg];
        if (wv == 0) sqpre = sqb[lane];
    }

    for (int chunk = 0; chunk < 64; ++chunk) {
        int m0 = chunk << 6;
        __syncthreads();   // prior-iter dw reads + B-frag reads done
        *(uint4*)&Bh[spt][seg * 8] = vh;
        *(uint4*)&Bl[spt][seg * 8] = vl;
        if (wv == 0) dsq[lane] = sqpre;
        __syncthreads();   // B staged

        if (chunk < 63) {
            int m1 = m0 + 64;
            const uint4* gh = (const uint4*)(xhb + ((size_t)(m1 + spt) << 6));
            const uint4* gl = (const uint4*)(xlb + ((size_t)(m1 + spt) << 6));
            vh = gh[seg]; vl = gl[seg];
            if (wv == 0) sqpre = sqb[m1 + lane];
        }

        // this wave's single tile: cands [16t, 16t+16), all 16 rows
        {
            int bp = (t << 4) + col;
            short8 bh0 = *(const short8*)&Bh[bp][quad * 8];
            short8 bh1 = *(const short8*)&Bh[bp][32 + quad * 8];
            short8 bl0 = *(const short8*)&Bl[bp][quad * 8];
            short8 bl1 = *(const short8*)&Bl[bp][32 + quad * 8];
            float4v acc = {0.f, 0.f, 0.f, 0.f};
            acc = __builtin_amdgcn_mfma_f32_16x16x32_bf16(ah0, bh0, acc, 0, 0, 0);
            acc = __builtin_amdgcn_mfma_f32_16x16x32_bf16(ah1, bh1, acc, 0, 0, 0);
            acc = __builtin_amdgcn_mfma_f32_16x16x32_bf16(ah0, bl0, acc, 0, 0, 0);
            acc = __builtin_amdgcn_mfma_f32_16x16x32_bf16(ah1, bl1, acc, 0, 0, 0);
            acc = __builtin_amdgcn_mfma_f32_16x16x32_bf16(al0, bh0, acc, 0, 0, 0);
            acc = __builtin_amdgcn_mfma_f32_16x16x32_bf16(al1, bh1, acc, 0, 0, 0);
            #pragma unroll
            for (int r = 0; r < 4; ++r)
                dw[g][(quad << 2) + r][(t << 4) + col] = acc[r];
        }
        __syncthreads();   // dw complete

        // scan rows [4t, 4t+4); lane = candidate
        float sv = dsq[lane];
        #pragma unroll
        for (int r = 0; r < 4; ++r) {
            float dval = fmaf(-2.f, dw[g][(t << 2) + r][lane], sv + sqr[r]);
            dval = fmaxf(dval, 0.f);
            uint key = (__float_as_uint(dval) & 0xFFFFF000u) | (uint)(m0 + lane);
            unsigned long long mask = __ballot(key < tau[r]);
            if (mask) {
                int c = __popcll(mask);
                if (cnt[r] + c > BUFCAP) {
                    tau[r] = select33_truncate(buf[r], cnt[r], lane);
                    mask = __ballot(key < tau[r]);
                    c = __popcll(mask);
                }
                if (c) {
                    int rank = mbcnt64(mask);
                    if (key < tau[r]) buf[r][cnt[r] + rank] = key;
                    cnt[r] += c;
                }
            }
        }
    }

    // final extraction: exact key-top-32 per row
    #pragma unroll
    for (int r = 0; r < 4; ++r) {
        select33_truncate(buf[r], cnt[r], lane);
        if (lane < KSEL) {
            uint e = buf[r][lane];
            knn32[(size_t)(b * NPTS + r0 + (t << 2) + r) * KSEL + lane] =
                (ushort)(e & 0xFFFu);
        }
    }
}

// ---------------------------------------------------------------------------
// K3: exact fp32 refinement — one wave per row; lanes (mod 32) hold the 32
// candidates, recompute exact fp32 distances, rank lexicographically
// (dist, idx) to match np's lower-index-first tie rule, emit top-20 set.
// ---------------------------------------------------------------------------
__global__ void __launch_bounds__(256) k_refine(
        const float* __restrict__ xt, const float* __restrict__ sq,
        const ushort* __restrict__ knn32, int* __restrict__ idx20) {
    int wid = (blockIdx.x << 2) + (threadIdx.x >> 6);  // row id [0, B*N)
    int lane = threadIdx.x & 63;
    int b = wid >> 12;
    int cand = knn32[(size_t)wid * KSEL + (lane & (KSEL - 1))];
    const float4* xc = (const float4*)(xt + ((size_t)(b * NPTS + cand) << 6));
    const float4* xr = (const float4*)(xt + ((size_t)wid << 6));
    float acc = 0.f;
    #pragma unroll
    for (int q = 0; q < 16; ++q) {
        float4 a = xr[q], c = xc[q];
        acc = fmaf(a.x, c.x, acc); acc = fmaf(a.y, c.y, acc);
        acc = fmaf(a.z, c.z, acc); acc = fmaf(a.w, c.w, acc);
    }
    float d = fmaf(-2.f, acc, sq[b * NPTS + cand]);
    int rank = 0;
    #pragma unroll
    for (int j = 0; j < KSEL; ++j) {
        float dj = __shfl(d, j);
        int   cj = __shfl(cand, j);
        rank += ((dj < d) || (dj == d && cj < cand)) ? 1 : 0;
    }
    if (lane < KSEL && rank < KNN)
        idx20[(size_t)wid * KNN + rank] = cand;
}

// ---------------------------------------------------------------------------
// K4: gather p columns per neighbor; per-(b,n) max/min/sum/sumsq over k;
// write tmax/tmin = (max/min_k p[idx]) + z; accumulate channel sums.
// ---------------------------------------------------------------------------
__global__ void k_gather(const float* __restrict__ pt, const float* __restrict__ zt,
                         const int* __restrict__ idxin,
                         float* __restrict__ tmax, float* __restrict__ tmin,
                         float* __restrict__ S1, float* __restrict__ S2) {
    __shared__ float red1[4][64];
    __shared__ float red2[4][64];
    int b  = blockIdx.x >> 6;
    int n0 = (blockIdx.x & 63) << 6;
    int lane = threadIdx.x & 63;
    int w = threadIdx.x >> 6;
    float cs1 = 0.f, cs2 = 0.f;
    for (int i = 0; i < 16; ++i) {
        int n = n0 + (w << 4) + i;
        int base = b * NPTS + n;
        int ibase = __builtin_amdgcn_readfirstlane(base * KNN);
        const int* ip = idxin + ibase;
        float mx = -FLT_MAX, mn = FLT_MAX, s1 = 0.f, s2 = 0.f;
        #pragma unroll
        for (int k = 0; k < KNN; ++k) {
            int colp = ip[k];                              // SGPR
            float v = pt[(((size_t)(b * NPTS + colp)) << 6) + lane]; // coalesced
            mx = fmaxf(mx, v); mn = fminf(mn, v);
            s1 += v; s2 = fmaf(v, v, s2);
        }
        float z = zt[(((size_t)base) << 6) + lane];
        tmax[(((size_t)base) << 6) + lane] = mx + z;
        tmin[(((size_t)base) << 6) + lane] = mn + z;
        cs1 += s1 + (float)KNN * z;
        cs2 += s2 + 2.f * z * s1 + (float)KNN * z * z;
    }
    red1[w][lane] = cs1;
    red2[w][lane] = cs2;
    __syncthreads();
    if (threadIdx.x < 64) {
        float t1 = red1[0][lane] + red1[1][lane] + red1[2][lane] + red1[3][lane];
        float t2 = red2[0][lane] + red2[1][lane] + red2[2][lane] + red2[3][lane];
        atomicAdd(&S1[lane], t1);
        atomicAdd(&S2[lane], t2);
    }
}

// ---------------------------------------------------------------------------
// K5: finalize BN stats, affine + LeakyReLU, transpose to out [B,64,N].
// ---------------------------------------------------------------------------
__global__ void k_final(const float* __restrict__ tmax, const float* __restrict__ tmin,
                        const float* __restrict__ S1, const float* __restrict__ S2,
                        const float* __restrict__ gamma, const float* __restrict__ beta,
                        float* __restrict__ out) {
    __shared__ float smx[64][65];
    __shared__ float smn[64][65];
    int b  = blockIdx.x >> 6;
    int n0 = (blockIdx.x & 63) << 6;
    int lane = threadIdx.x & 63;
    int w = threadIdx.x >> 6;
    #pragma unroll
    for (int i = 0; i < 16; ++i) {
        int nl = (i << 2) + w;
        size_t off = (((size_t)(b * NPTS + n0 + nl)) << 6) + lane;
        smx[nl][lane] = tmax[off];
        smn[nl][lane] = tmin[off];
    }
    __syncthreads();
    const float inv_cnt = 1.0f / ((float)BATCH * NPTS * KNN);
    #pragma unroll
    for (int i = 0; i < 16; ++i) {
        int o = (i << 2) + w;
        float s1 = S1[o], s2 = S2[o];
        float mean = s1 * inv_cnt;
        float var = fmaf(-mean, mean, s2 * inv_cnt);
        float rs = rsqrtf(var + BN_EPS);
        float sc = gamma[o] * rs;
        float sh = beta[o] - mean * sc;
        float tv = (sc >= 0.f) ? smx[lane][o] : smn[lane][o];
        float y = fmaf(tv, sc, sh);
        y = (y >= 0.f) ? y : NEG_SLOPE * y;
        out[((size_t)(b * 64 + o)) * NPTS + n0 + lane] = y;
    }
}

// ---------------------------------------------------------------------------
extern "C" void kernel_launch(void* const* d_in, const int* in_sizes, int n_in,
                              void* d_out, int out_size, void* d_ws, size_t ws_size,
                              hipStream_t stream) {
    const float* x     = (const float*)d_in[0];   // [8,64,4096]
    const float* W     = (const float*)d_in[1];   // [64,128]
    const float* gamma = (const float*)d_in[2];   // [64]
    const float* beta  = (const float*)d_in[3];   // [64]
    float* out = (float*)d_out;                   // [8,64,4096]

    float* ws = (float*)d_ws;
    const size_t SECT = (size_t)BATCH * NPTS * 64;      // 2,097,152
    float*  xt    = ws;
    float*  pt    = ws + SECT;
    float*  zt    = ws + 2 * SECT;
    float*  sq    = ws + 3 * SECT;                       // 32768
    float*  S1    = ws + 3 * SECT + 32768;               // 64
    float*  S2    = S1 + 64;
    int*    idx20 = (int*)(ws + 3 * SECT + 32768 + 128); // 655,360 ints
    float*  uA    = ws + 3 * SECT + 32768 + 128 + 655360;
    // union A:
    //   phase 1 (prep..refine): xh | xl | knn32(ushort, B*N*32)
    //   phase 2 (gather..final): tmx | tmn
    ushort* xh    = (ushort*)uA;                         // SECT ushorts
    ushort* xl    = (ushort*)(uA + SECT / 2);            // SECT ushorts
    ushort* knn32 = (ushort*)(uA + SECT);                // B*N*32 ushorts
    float*  tmx   = uA;                                  // SECT floats
    float*  tmn   = uA + SECT;                           // SECT floats
    // total ws use: ~44.7 MB

    hipMemsetAsync(S1, 0, 2 * 64 * sizeof(float), stream);
    k_prep  <<<dim3((BATCH * NPTS) / 256), dim3(256), 0, stream>>>(x, W, xt, xh, xl, sq, pt, zt);
    k_knn   <<<dim3(1024), dim3(512), 0, stream>>>(xh, xl, sq, knn32);
    k_refine<<<dim3((BATCH * NPTS) / 4), dim3(256), 0, stream>>>(xt, sq, knn32, idx20);
    k_gather<<<dim3(BATCH * (NPTS / 64)), dim3(256), 0, stream>>>(pt, zt, idx20, tmx, tmn, S1, S2);
    k_final <<<dim3(BATCH * (NPTS / 64)), dim3(256), 0, stream>>>(tmx, tmn, S1, S2, gamma, beta, out);
}

// Round 10
// 511.608 us; speedup vs baseline: 2.1662x; 1.0336x over previous
//
#include <hip/hip_runtime.h>
#include <hip/hip_bf16.h>
#include <float.h>

#define BATCH 8
#define CDIM 64
#define NPTS 4096
#define KNN 20
#define KSEL 32
#define BUFCAP 80
#define BN_EPS 1e-5f
#define NEG_SLOPE 0.2f

typedef __attribute__((ext_vector_type(8))) short short8;
typedef __attribute__((ext_vector_type(4))) float float4v;
typedef unsigned short ushort;
typedef unsigned int uint;

__device__ __forceinline__ ushort f2bf(float f) {
    uint u = __float_as_uint(f);
    u += 0x7FFF + ((u >> 16) & 1);            // round-to-nearest-even
    return (ushort)(u >> 16);
}
__device__ __forceinline__ float bf2f(ushort h) {
    return __uint_as_float(((uint)h) << 16);
}
__device__ __forceinline__ int mbcnt64(unsigned long long m) {
    int c = __builtin_amdgcn_mbcnt_lo((uint)m, 0);
    return __builtin_amdgcn_mbcnt_hi((uint)(m >> 32), c);
}

// Select the 32 smallest keys of {buf[0..cnt)} U {key[lane] | key!=INF},
// compact them to buf front (original order preserved within sources),
// set cnt to kept count, return K33 (new tau). Capacity-safe: result <= 32.
__device__ __forceinline__ uint select33_merge(uint* __restrict__ buf,
                                               int& cnt, int lane, uint key) {
    uint e0 = (lane < cnt)      ? buf[lane]      : 0xFFFFFFFFu;
    uint e1 = (64 + lane < cnt) ? buf[64 + lane] : 0xFFFFFFFFu;
    uint e2 = key;
    uint p = 0;
    for (int bit = 31; bit >= 0; --bit) {
        uint t = p | (1u << bit);
        int c = __popcll(__ballot(e0 < t)) + __popcll(__ballot(e1 < t))
              + __popcll(__ballot(e2 < t));
        if (c < 33) p = t;   // uniform
    }
    unsigned long long m0 = __ballot(e0 < p);
    unsigned long long m1 = __ballot(e1 < p);
    unsigned long long m2 = __ballot(e2 < p);
    int c0 = __popcll(m0), c1 = __popcll(m1);
    int r0 = mbcnt64(m0);
    int r1 = c0 + mbcnt64(m1);
    int r2 = c0 + c1 + mbcnt64(m2);
    if (e0 < p) buf[r0] = e0;
    if (e1 < p) buf[r1] = e1;
    if (e2 < p) buf[r2] = e2;
    cnt = c0 + c1 + __popcll(m2);
    return p;
}

// ---------------------------------------------------------------------------
// K1: x [B,C,N] -> xt [B,N,64] fp32, xh/xl bf16 hi/lo split, sq[b,n].
// ---------------------------------------------------------------------------
__global__ void k_prep(const float* __restrict__ x,
                       float* __restrict__ xt,
                       ushort* __restrict__ xh,
                       ushort* __restrict__ xl,
                       float* __restrict__ sq) {
    int gid = blockIdx.x * 256 + threadIdx.x;     // [0, B*N)
    int b = gid >> 12;
    int n = gid & (NPTS - 1);
    const float* xb = x + (size_t)b * CDIM * NPTS + n;
    float acc = 0.f;
    float4* xtv = (float4*)(xt + ((size_t)gid << 6));
    uint2* xhp = (uint2*)(xh + ((size_t)gid << 6));
    uint2* xlp = (uint2*)(xl + ((size_t)gid << 6));
    #pragma unroll
    for (int q = 0; q < 16; ++q) {
        float v[4]; ushort h[4], l[4];
        #pragma unroll
        for (int j = 0; j < 4; ++j) {
            float tv = xb[(q * 4 + j) * NPTS];    // coalesced across n
            v[j] = tv;
            acc = fmaf(tv, tv, acc);
            h[j] = f2bf(tv);
            l[j] = f2bf(tv - bf2f(h[j]));
        }
        xtv[q] = make_float4(v[0], v[1], v[2], v[3]);
        uint2 ph, pl;
        ph.x = (uint)h[0] | ((uint)h[1] << 16);
        ph.y = (uint)h[2] | ((uint)h[3] << 16);
        pl.x = (uint)l[0] | ((uint)l[1] << 16);
        pl.y = (uint)l[2] | ((uint)l[3] << 16);
        xhp[q] = ph;
        xlp[q] = pl;
    }
    sq[gid] = acc;
}

// ---------------------------------------------------------------------------
// K2: p = W1 @ x, z = (W2-W1) @ x, stored transposed: pt/zt [B,N,64]
// ---------------------------------------------------------------------------
__global__ void k_pz(const float* __restrict__ xt, const float* __restrict__ W,
                     float* __restrict__ pt, float* __restrict__ zt) {
    int b  = blockIdx.x >> 6;
    int n0 = (blockIdx.x & 63) << 6;
    int lane = threadIdx.x & 63;
    int w = threadIdx.x >> 6;
    int n = n0 + lane;
    size_t rowoff = ((size_t)(b * NPTS + n)) << 6;
    const float4* xrow = (const float4*)(xt + rowoff);
    float acc1[16], acc2[16];
    #pragma unroll
    for (int i = 0; i < 16; ++i) { acc1[i] = 0.f; acc2[i] = 0.f; }
    #pragma unroll
    for (int cg = 0; cg < 4; ++cg) {
        float xv[16];
        #pragma unroll
        for (int q = 0; q < 4; ++q) {
            float4 t = xrow[cg * 4 + q];
            xv[q*4] = t.x; xv[q*4+1] = t.y; xv[q*4+2] = t.z; xv[q*4+3] = t.w;
        }
        #pragma unroll
        for (int oi = 0; oi < 16; ++oi) {
            int o = (w << 4) + oi;
            const float* wr = W + o * 128 + cg * 16;
            float a1 = acc1[oi], a2 = acc2[oi];
            #pragma unroll
            for (int j = 0; j < 16; ++j) {
                a1 = fmaf(wr[j],      xv[j], a1);
                a2 = fmaf(wr[64 + j], xv[j], a2);
            }
            acc1[oi] = a1; acc2[oi] = a2;
        }
    }
    float4* pv = (float4*)(pt + rowoff + (w << 4));
    float4* zv = (float4*)(zt + rowoff + (w << 4));
    #pragma unroll
    for (int q = 0; q < 4; ++q) {
        pv[q] = make_float4(acc1[q*4], acc1[q*4+1], acc1[q*4+2], acc1[q*4+3]);
        zv[q] = make_float4(acc2[q*4]   - acc1[q*4],
                            acc2[q*4+1] - acc1[q*4+1],
                            acc2[q*4+2] - acc1[q*4+2],
                            acc2[q*4+3] - acc1[q*4+3]);
    }
}

// ---------------------------------------------------------------------------
// K3: split-bf16 MFMA kNN + fused exact refine. 128-candidate chunks (32
// iterations), block = 8 waves over 2 row-groups of 16 rows; wave t computes
// tiles {t, t+4} into the group dw, then scans rows [4t,4t+4) via packed-key
// (20-bit dist | 12-bit idx) mbcnt-append into an 80-entry LDS buffer/row;
// capacity-safe 3-source merge-select on overflow. Tail: exact select-32,
// then exact fp32 re-rank (np tie rule) writing top-20 indices directly.
// ---------------------------------------------------------------------------
__global__ void __launch_bounds__(512, 4) k_knn(
        const ushort* __restrict__ xh, const ushort* __restrict__ xl,
        const float* __restrict__ sq, const float* __restrict__ xt,
        int* __restrict__ idx20) {
    __shared__ ushort Bh[128][72];    // 18.4 KB (+8 pad, keeps b128 16B-aligned)
    __shared__ ushort Bl[128][72];    // 18.4 KB
    __shared__ float dsq[128];
    __shared__ float dw[2][16][132];  // 16.9 KB, per-group dist tile
    __shared__ uint rowbuf[32 * BUFCAP];   // 10.2 KB; total 64,512 B

    int tid  = threadIdx.x;
    int wv   = tid >> 6;              // wave 0..7
    int lane = tid & 63;
    int g    = wv >> 2;               // row-group 0..1
    int t    = wv & 3;                // wave-in-group
    int b    = blockIdx.x >> 7;       // 128 blocks per batch
    int r0   = ((blockIdx.x & 127) << 5) + (g << 4);   // group base row
    int col  = lane & 15;
    int quad = lane >> 4;

    // A fragments (chunk-invariant): row = r0 + col, k = quad*8 + j
    size_t arow = ((size_t)(b * NPTS + r0 + col)) << 6;
    short8 ah0 = *(const short8*)(xh + arow + quad * 8);
    short8 ah1 = *(const short8*)(xh + arow + 32 + quad * 8);
    short8 al0 = *(const short8*)(xl + arow + quad * 8);
    short8 al1 = *(const short8*)(xl + arow + 32 + quad * 8);

    const ushort* xhb = xh + (((size_t)b * NPTS) << 6);
    const ushort* xlb = xl + (((size_t)b * NPTS) << 6);
    const float* sqb = sq + b * NPTS;
    int spt = tid >> 2, seg = tid & 3;    // 128 pts x 2 segs of 8 ushorts each

    uint tau[4];
    int cnt[4];
    float sqr[4];
    uint* buf[4];
    #pragma unroll
    for (int r = 0; r < 4; ++r) {
        tau[r] = 0xFFFFFFFFu; cnt[r] = 0;
        sqr[r] = sqb[r0 + (t << 2) + r];
        buf[r] = rowbuf + ((wv << 2) + r) * BUFCAP;
    }

    // prefetch chunk 0
    uint4 vh0, vh1, vl0, vl1; float sqpre = 0.f;
    {
        const uint4* gh = (const uint4*)(xhb + ((size_t)spt << 6));
        const uint4* gl = (const uint4*)(xlb + ((size_t)spt << 6));
        vh0 = gh[seg]; vh1 = gh[seg + 4];
        vl0 = gl[seg]; vl1 = gl[seg + 4];
        if (tid < 128) sqpre = sqb[tid];
    }

    for (int chunk = 0; chunk < 32; ++chunk) {
        int m0 = chunk << 7;
        __syncthreads();   // prior-iter dw/B-frag reads done before restage
        *(uint4*)&Bh[spt][seg * 8]        = vh0;
        *(uint4*)&Bh[spt][(seg + 4) * 8]  = vh1;
        *(uint4*)&Bl[spt][seg * 8]        = vl0;
        *(uint4*)&Bl[spt][(seg + 4) * 8]  = vl1;
        if (tid < 128) dsq[tid] = sqpre;
        __syncthreads();   // B staged

        if (chunk < 31) {
            int m1 = m0 + 128;
            const uint4* gh = (const uint4*)(xhb + ((size_t)(m1 + spt) << 6));
            const uint4* gl = (const uint4*)(xlb + ((size_t)(m1 + spt) << 6));
            vh0 = gh[seg]; vh1 = gh[seg + 4];
            vl0 = gl[seg]; vl1 = gl[seg + 4];
            if (tid < 128) sqpre = sqb[m1 + tid];
        }

        // this wave's two tiles: cands [16u, 16u+16), u in {t, t+4}
        #pragma unroll
        for (int ui = 0; ui < 2; ++ui) {
            int u = t + ui * 4;
            int bp = (u << 4) + col;
            short8 bh0 = *(const short8*)&Bh[bp][quad * 8];
            short8 bh1 = *(const short8*)&Bh[bp][32 + quad * 8];
            short8 bl0 = *(const short8*)&Bl[bp][quad * 8];
            short8 bl1 = *(const short8*)&Bl[bp][32 + quad * 8];
            float4v acc = {0.f, 0.f, 0.f, 0.f};
            acc = __builtin_amdgcn_mfma_f32_16x16x32_bf16(ah0, bh0, acc, 0, 0, 0);
            acc = __builtin_amdgcn_mfma_f32_16x16x32_bf16(ah1, bh1, acc, 0, 0, 0);
            acc = __builtin_amdgcn_mfma_f32_16x16x32_bf16(ah0, bl0, acc, 0, 0, 0);
            acc = __builtin_amdgcn_mfma_f32_16x16x32_bf16(ah1, bl1, acc, 0, 0, 0);
            acc = __builtin_amdgcn_mfma_f32_16x16x32_bf16(al0, bh0, acc, 0, 0, 0);
            acc = __builtin_amdgcn_mfma_f32_16x16x32_bf16(al1, bh1, acc, 0, 0, 0);
            #pragma unroll
            for (int r = 0; r < 4; ++r)
                dw[g][(quad << 2) + r][(u << 4) + col] = acc[r];
        }
        __syncthreads();   // dw complete for both groups

        // scan rows [4t, 4t+4); lane = candidate, two 64-cand passes
        float sv0 = dsq[lane];
        float sv1 = dsq[64 + lane];
        #pragma unroll
        for (int r = 0; r < 4; ++r) {
            int rg2 = (t << 2) + r;
            #pragma unroll
            for (int hh = 0; hh < 2; ++hh) {
                float sv = hh ? sv1 : sv0;
                float dval = fmaf(-2.f, dw[g][rg2][(hh << 6) + lane], sv + sqr[r]);
                dval = fmaxf(dval, 0.f);
                uint key = (__float_as_uint(dval) & 0xFFFFF000u)
                         | (uint)(m0 + (hh << 6) + lane);
                unsigned long long mask = __ballot(key < tau[r]);
                if (mask) {
                    int c = __popcll(mask);
                    if (cnt[r] + c > BUFCAP) {
                        // capacity-safe merge: buffer + current candidates
                        tau[r] = select33_merge(buf[r], cnt[r], lane,
                                    (key < tau[r]) ? key : 0xFFFFFFFFu);
                    } else {
                        int rank = mbcnt64(mask);
                        if (key < tau[r]) buf[r][cnt[r] + rank] = key;
                        cnt[r] += c;
                    }
                }
            }
        }
    }

    // tail: exact select-32 per row, then exact fp32 re-rank (np tie rule)
    #pragma unroll
    for (int r = 0; r < 4; ++r) {
        select33_merge(buf[r], cnt[r], lane, 0xFFFFFFFFu);
        int row = b * NPTS + r0 + (t << 2) + r;
        int cand = (int)(buf[r][lane & 31] & 0xFFFu);
        const float4* xc = (const float4*)(xt + ((size_t)(b * NPTS + cand) << 6));
        const float4* xr = (const float4*)(xt + ((size_t)row << 6));
        float acc = 0.f;
        #pragma unroll
        for (int q = 0; q < 16; ++q) {
            float4 a = xr[q], c4 = xc[q];
            acc = fmaf(a.x, c4.x, acc); acc = fmaf(a.y, c4.y, acc);
            acc = fmaf(a.z, c4.z, acc); acc = fmaf(a.w, c4.w, acc);
        }
        float d = fmaf(-2.f, acc, sqb[cand]);
        int rank = 0;
        #pragma unroll
        for (int j = 0; j < KSEL; ++j) {
            float dj = __shfl(d, j);
            int   cj = __shfl(cand, j);
            rank += ((dj < d) || (dj == d && cj < cand)) ? 1 : 0;
        }
        if (lane < KSEL && rank < KNN)
            idx20[(size_t)row * KNN + rank] = cand;
    }
}

// ---------------------------------------------------------------------------
// K4: gather p columns per neighbor; per-(b,n) max/min/sum/sumsq over k;
// write tmax/tmin = (max/min_k p[idx]) + z; accumulate channel sums.
// ---------------------------------------------------------------------------
__global__ void k_gather(const float* __restrict__ pt, const float* __restrict__ zt,
                         const int* __restrict__ idxin,
                         float* __restrict__ tmax, float* __restrict__ tmin,
                         float* __restrict__ S1, float* __restrict__ S2) {
    __shared__ float red1[4][64];
    __shared__ float red2[4][64];
    int b  = blockIdx.x >> 6;
    int n0 = (blockIdx.x & 63) << 6;
    int lane = threadIdx.x & 63;
    int w = threadIdx.x >> 6;
    float cs1 = 0.f, cs2 = 0.f;
    for (int i = 0; i < 16; ++i) {
        int n = n0 + (w << 4) + i;
        int base = b * NPTS + n;
        int ibase = __builtin_amdgcn_readfirstlane(base * KNN);
        const int* ip = idxin + ibase;
        float mx = -FLT_MAX, mn = FLT_MAX, s1 = 0.f, s2 = 0.f;
        #pragma unroll
        for (int k = 0; k < KNN; ++k) {
            int colp = ip[k];                              // SGPR
            float v = pt[(((size_t)(b * NPTS + colp)) << 6) + lane]; // coalesced
            mx = fmaxf(mx, v); mn = fminf(mn, v);
            s1 += v; s2 = fmaf(v, v, s2);
        }
        float z = zt[(((size_t)base) << 6) + lane];
        tmax[(((size_t)base) << 6) + lane] = mx + z;
        tmin[(((size_t)base) << 6) + lane] = mn + z;
        cs1 += s1 + (float)KNN * z;
        cs2 += s2 + 2.f * z * s1 + (float)KNN * z * z;
    }
    red1[w][lane] = cs1;
    red2[w][lane] = cs2;
    __syncthreads();
    if (threadIdx.x < 64) {
        float t1 = red1[0][lane] + red1[1][lane] + red1[2][lane] + red1[3][lane];
        float t2 = red2[0][lane] + red2[1][lane] + red2[2][lane] + red2[3][lane];
        atomicAdd(&S1[lane], t1);
        atomicAdd(&S2[lane], t2);
    }
}

// ---------------------------------------------------------------------------
// K5: finalize BN stats, affine + LeakyReLU, transpose to out [B,64,N].
// ---------------------------------------------------------------------------
__global__ void k_final(const float* __restrict__ tmax, const float* __restrict__ tmin,
                        const float* __restrict__ S1, const float* __restrict__ S2,
                        const float* __restrict__ gamma, const float* __restrict__ beta,
                        float* __restrict__ out) {
    __shared__ float smx[64][65];
    __shared__ float smn[64][65];
    int b  = blockIdx.x >> 6;
    int n0 = (blockIdx.x & 63) << 6;
    int lane = threadIdx.x & 63;
    int w = threadIdx.x >> 6;
    #pragma unroll
    for (int i = 0; i < 16; ++i) {
        int nl = (i << 2) + w;
        size_t off = (((size_t)(b * NPTS + n0 + nl)) << 6) + lane;
        smx[nl][lane] = tmax[off];
        smn[nl][lane] = tmin[off];
    }
    __syncthreads();
    const float inv_cnt = 1.0f / ((float)BATCH * NPTS * KNN);
    #pragma unroll
    for (int i = 0; i < 16; ++i) {
        int o = (i << 2) + w;
        float s1 = S1[o], s2 = S2[o];
        float mean = s1 * inv_cnt;
        float var = fmaf(-mean, mean, s2 * inv_cnt);
        float rs = rsqrtf(var + BN_EPS);
        float sc = gamma[o] * rs;
        float sh = beta[o] - mean * sc;
        float tv = (sc >= 0.f) ? smx[lane][o] : smn[lane][o];
        float y = fmaf(tv, sc, sh);
        y = (y >= 0.f) ? y : NEG_SLOPE * y;
        out[((size_t)(b * 64 + o)) * NPTS + n0 + lane] = y;
    }
}

// ---------------------------------------------------------------------------
extern "C" void kernel_launch(void* const* d_in, const int* in_sizes, int n_in,
                              void* d_out, int out_size, void* d_ws, size_t ws_size,
                              hipStream_t stream) {
    const float* x     = (const float*)d_in[0];   // [8,64,4096]
    const float* W     = (const float*)d_in[1];   // [64,128]
    const float* gamma = (const float*)d_in[2];   // [64]
    const float* beta  = (const float*)d_in[3];   // [64]
    float* out = (float*)d_out;                   // [8,64,4096]

    float* ws = (float*)d_ws;
    const size_t SECT = (size_t)BATCH * NPTS * 64;      // 2,097,152
    float*  xt    = ws;
    float*  pt    = ws + SECT;
    float*  zt    = ws + 2 * SECT;
    float*  sq    = ws + 3 * SECT;                       // 32768
    float*  S1    = ws + 3 * SECT + 32768;               // 64
    float*  S2    = S1 + 64;
    int*    idx20 = (int*)(ws + 3 * SECT + 32768 + 128); // 655,360 ints
    float*  uA    = ws + 3 * SECT + 32768 + 128 + 655360;
    // union A:
    //   phase 1 (prep..knn): xh | xl bf16 splits
    //   phase 2 (gather..final): tmx | tmn
    ushort* xh    = (ushort*)uA;                         // SECT ushorts
    ushort* xl    = (ushort*)(uA + SECT / 2);            // SECT ushorts
    float*  tmx   = uA;                                  // SECT floats
    float*  tmn   = uA + SECT;                           // SECT floats
    // total ws use: ~44.7 MB

    hipMemsetAsync(S1, 0, 2 * 64 * sizeof(float), stream);
    k_prep  <<<dim3((BATCH * NPTS) / 256), dim3(256), 0, stream>>>(x, xt, xh, xl, sq);
    k_pz    <<<dim3(BATCH * (NPTS / 64)), dim3(256), 0, stream>>>(xt, W, pt, zt);
    k_knn   <<<dim3(1024), dim3(512), 0, stream>>>(xh, xl, sq, xt, idx20);
    k_gather<<<dim3(BATCH * (NPTS / 64)), dim3(256), 0, stream>>>(pt, zt, idx20, tmx, tmn, S1, S2);
    k_final <<<dim3(BATCH * (NPTS / 64)), dim3(256), 0, stream>>>(tmx, tmn, S1, S2, gamma, beta, out);
}